// Round 1
// baseline (692.479 us; speedup 1.0000x reference)
//
#include <hip/hip_runtime.h>
#include <cstddef>

#define PI_F 3.14159265358979323846f
#define TOTAL_TEX 349440
#define NC 32

__constant__ int c_offs[6] = {0, 262144, 327680, 344064, 348160, 349184};

// ---------------------------------------------------------------------------
// K1: transpose feature (C,6,512,512) -> pool_t level0 [6][512*512][C]
//     and produce pooled1 [6][256*256][C] (2x2 avg) in the same pass.
// One block = one face x 16x16 pixel tile, all 32 channels via LDS.
// LDS layout tile[(y*16+x)*33 + c]  (+1 pad in c => conflict-free both phases)
// ---------------------------------------------------------------------------
__global__ __launch_bounds__(256) void k_transpose_pool(
    const float* __restrict__ feat, float* __restrict__ pool_t,
    float* __restrict__ pooled1)
{
  __shared__ float tile[256 * 33];
  int blk = blockIdx.x;
  int f = blk >> 10;          // 1024 tiles per face
  int t = blk & 1023;
  int gy0 = (t >> 5) << 4;
  int gx0 = (t & 31) << 4;
  int tid = threadIdx.x;
  int ly = tid >> 4, lx = tid & 15;

  // load: coalesced along x, loop channels
  for (int c = 0; c < NC; ++c) {
    tile[(ly * 16 + lx) * 33 + c] =
        feat[(((size_t)c * 6 + f) * 512 + (gy0 + ly)) * 512 + (gx0 + lx)];
  }
  __syncthreads();

  // level-0 transposed write: contiguous 512-float runs per tile row
  size_t base0 = ((size_t)f * TOTAL_TEX + (size_t)gy0 * 512 + gx0) * NC;
  for (int it = 0; it < 32; ++it) {
    int e = it * 256 + tid;
    int c = e & 31;
    int x = (e >> 5) & 15;
    int y = e >> 9;
    pool_t[base0 + ((size_t)y * 512 + x) * NC + c] = tile[(y * 16 + x) * 33 + c];
  }

  // pooled level-1 (2x2 mean), 8x8 pixels x 32 ch
  size_t base1 = ((size_t)f * 65536 + (size_t)(gy0 >> 1) * 256 + (gx0 >> 1)) * NC;
  for (int it = 0; it < 8; ++it) {
    int e = it * 256 + tid;
    int c = e & 31;
    int x1 = (e >> 5) & 7;
    int y1 = e >> 8;
    float v = 0.25f * ((tile[((2 * y1) * 16 + 2 * x1) * 33 + c] +
                        tile[((2 * y1) * 16 + 2 * x1 + 1) * 33 + c]) +
                       (tile[((2 * y1 + 1) * 16 + 2 * x1) * 33 + c] +
                        tile[((2 * y1 + 1) * 16 + 2 * x1 + 1) * 33 + c]));
    pooled1[base1 + ((size_t)y1 * 256 + x1) * NC + c] = v;
  }
}

// ---------------------------------------------------------------------------
// K2: generic 2x2 avg pool, both sides [6][R*R][C] channel-innermost.
// ---------------------------------------------------------------------------
__global__ __launch_bounds__(256) void k_pool(
    const float* __restrict__ in, float* __restrict__ out,
    int Rin, int logRout, int n)
{
  int t = blockIdx.x * 256 + threadIdx.x;
  if (t >= n) return;
  int c = t & 31;
  int rem = t >> 5;
  int Rout = Rin >> 1;
  int x = rem & (Rout - 1);
  rem >>= logRout;
  int y = rem & (Rout - 1);
  int f = rem >> logRout;
  size_t b = (((size_t)f * Rin + 2 * y) * Rin + 2 * x) * NC + c;
  size_t rowstep = (size_t)Rin * NC;
  out[t] = 0.25f * ((in[b] + in[b + NC]) + (in[b + rowstep] + in[b + rowstep + NC]));
}

// ---------------------------------------------------------------------------
// K3: 5x5 GGX specular filter. One thread = one (face,pixel), all 32 channels.
// Weights computed once per pixel-tap (shared across channels in-register).
// ---------------------------------------------------------------------------
__device__ inline float3 face_dir_norm(int f, int i, int j, float inv2R)
{
  float u = ((float)j + 0.5f) * inv2R - 1.0f;  // uu = t[j]
  float v = ((float)i + 0.5f) * inv2R - 1.0f;  // vv = t[i]
  float x, y, z;
  switch (f) {
    case 0: x = 1.0f;  y = -v; z = -u;   break;
    case 1: x = -1.0f; y = -v; z = u;    break;
    case 2: x = u;  y = 1.0f;  z = v;    break;
    case 3: x = u;  y = -1.0f; z = -v;   break;
    case 4: x = u;  y = -v;    z = 1.0f; break;
    default: x = -u; y = -v;   z = -1.0f; break;
  }
  float s = 1.0f / sqrtf(x * x + y * y + z * z);
  float3 o; o.x = x * s; o.y = y * s; o.z = z * s;
  return o;
}

__global__ __launch_bounds__(256) void k_filter(
    const float* __restrict__ in, float* __restrict__ out,
    int R, int logR, float a2, int n)
{
  int t = blockIdx.x * 256 + threadIdx.x;
  if (t >= n) return;
  int j = t & (R - 1);
  int i = (t >> logR) & (R - 1);
  int f = t >> (2 * logR);
  float inv2R = 2.0f / (float)R;
  float3 dc = face_dir_norm(f, i, j, inv2R);

  float4 acc[8];
#pragma unroll
  for (int k = 0; k < 8; ++k) { acc[k].x = acc[k].y = acc[k].z = acc[k].w = 0.0f; }
  float wsum = 0.0f;

  for (int di = -2; di <= 2; ++di) {
    int ii = min(max(i + di, 0), R - 1);
    for (int dj = -2; dj <= 2; ++dj) {
      int jj = min(max(j + dj, 0), R - 1);
      float3 dn = face_dir_norm(f, ii, jj, inv2R);
      float cs = dc.x * dn.x + dc.y * dn.y + dc.z * dn.z;
      cs = fminf(fmaxf(cs, -1.0f), 1.0f);
      float den = cs * cs * (a2 - 1.0f) + 1.0f;
      float w = (cs > 0.0f) ? (a2 / (PI_F * den * den)) : 0.0f;
      wsum += w;
      const float4* p = (const float4*)(in + (((size_t)f << (2 * logR)) + (size_t)ii * R + jj) * NC);
#pragma unroll
      for (int k = 0; k < 8; ++k) {
        float4 q = p[k];
        acc[k].x += w * q.x; acc[k].y += w * q.y;
        acc[k].z += w * q.z; acc[k].w += w * q.w;
      }
    }
  }
  float s = 1.0f / fmaxf(wsum, 1e-8f);
  float4* o = (float4*)(out + ((size_t)f * TOTAL_TEX + (size_t)i * R + j) * NC);
#pragma unroll
  for (int k = 0; k < 8; ++k) {
    float4 q; q.x = acc[k].x * s; q.y = acc[k].y * s; q.z = acc[k].z * s; q.w = acc[k].w * s;
    o[k] = q;
  }
}

// ---------------------------------------------------------------------------
// K4: fetch. One thread = one sample, all 32 channels (8 float4 accumulators).
// Gathers 8 texels (4 bilinear x 2 mip levels) of 128B each.
// ---------------------------------------------------------------------------
__global__ __launch_bounds__(256) void k_fetch(
    const float* __restrict__ pool_t, const float* __restrict__ wv,
    const float* __restrict__ rv, float* __restrict__ out, int B)
{
  int b = blockIdx.x * 256 + threadIdx.x;
  if (b >= B) return;
  float dx = wv[3 * b + 0] * 2.0f - 1.0f;
  float dy = wv[3 * b + 1] * 2.0f - 1.0f;
  float dz = wv[3 * b + 2] * 2.0f - 1.0f;
  // normalization cancels in all ratios/sign tests -> skip it
  float ax = fabsf(dx), ay = fabsf(dy), az = fabsf(dz);
  bool condx = (ax >= ay) && (ax >= az);
  bool condy = (ay >= az) && !condx;
  float ma = condx ? ax : (condy ? ay : az);
  int face = condx ? (dx > 0.0f ? 0 : 1)
                   : (condy ? (dy > 0.0f ? 2 : 3) : (dz > 0.0f ? 4 : 5));
  float un = condx ? (dx > 0.0f ? -dz : dz)
                   : (condy ? dx : (dz > 0.0f ? dx : -dx));
  float vn = condx ? -dy : (condy ? (dy > 0.0f ? dz : -dz) : -dy);
  float u01 = (un / ma + 1.0f) * 0.5f;
  float v01 = (vn / ma + 1.0f) * 0.5f;

  float rr = rv[b];
  float lev_f = fminf(fmaxf((rr - 0.03f) / (0.99f - 0.03f), 0.0f), 1.0f) * 5.0f;
  int l0 = (int)floorf(lev_f);
  l0 = min(max(l0, 0), 5);
  int l1 = min(l0 + 1, 5);
  float tt = lev_f - (float)l0;

  float4 acc[8];
#pragma unroll
  for (int k = 0; k < 8; ++k) { acc[k].x = acc[k].y = acc[k].z = acc[k].w = 0.0f; }

  int lv0 = l0, lv1 = l1;
  float lw0 = 1.0f - tt, lw1 = tt;
#pragma unroll 1
  for (int s = 0; s < 2; ++s) {
    int l = s == 0 ? lv0 : lv1;
    float wl = s == 0 ? lw0 : lw1;
    int res = 512 >> l;
    float rf = (float)res;
    float x = fminf(fmaxf(u01 * rf - 0.5f, 0.0f), rf - 1.0f);
    float y = fminf(fmaxf(v01 * rf - 0.5f, 0.0f), rf - 1.0f);
    int x0 = (int)floorf(x), y0 = (int)floorf(y);
    int x1 = min(x0 + 1, res - 1), y1 = min(y0 + 1, res - 1);
    float fx = x - (float)x0, fy = y - (float)y0;
    size_t base = ((size_t)face * TOTAL_TEX + c_offs[l]) * NC;
    const float4* p00 = (const float4*)(pool_t + base + ((size_t)y0 * res + x0) * NC);
    const float4* p01 = (const float4*)(pool_t + base + ((size_t)y0 * res + x1) * NC);
    const float4* p10 = (const float4*)(pool_t + base + ((size_t)y1 * res + x0) * NC);
    const float4* p11 = (const float4*)(pool_t + base + ((size_t)y1 * res + x1) * NC);
    float w00 = wl * (1.0f - fx) * (1.0f - fy);
    float w01 = wl * fx * (1.0f - fy);
    float w10 = wl * (1.0f - fx) * fy;
    float w11 = wl * fx * fy;
#pragma unroll
    for (int k = 0; k < 8; ++k) {
      float4 a = p00[k], bq = p01[k], cq = p10[k], dq = p11[k];
      acc[k].x += w00 * a.x + w01 * bq.x + w10 * cq.x + w11 * dq.x;
      acc[k].y += w00 * a.y + w01 * bq.y + w10 * cq.y + w11 * dq.y;
      acc[k].z += w00 * a.z + w01 * bq.z + w10 * cq.z + w11 * dq.z;
      acc[k].w += w00 * a.w + w01 * bq.w + w10 * cq.w + w11 * dq.w;
    }
  }
  float4* o = (float4*)(out + (size_t)b * NC);
#pragma unroll
  for (int k = 0; k < 8; ++k) o[k] = acc[k];
}

// ---------------------------------------------------------------------------
extern "C" void kernel_launch(void* const* d_in, const int* in_sizes, int n_in,
                              void* d_out, int out_size, void* d_ws, size_t ws_size,
                              hipStream_t stream)
{
  const float* feat = (const float*)d_in[0];
  const float* wv   = (const float*)d_in[1];
  const float* rv   = (const float*)d_in[2];
  float* out = (float*)d_out;
  int B = in_sizes[1] / 3;

  // workspace layout (floats):
  //   [0, 6*TOTAL*32)                  pool_t  (268.4 MB)
  //   then pooled scratch levels 1..5  (67.0 MB)
  float* pool_t = (float*)d_ws;
  const size_t POOLT = (size_t)6 * TOTAL_TEX * NC;
  float* pooled1 = pool_t + POOLT;
  float* pooled2 = pooled1 + (size_t)6 * 256 * 256 * NC;
  float* pooled3 = pooled2 + (size_t)6 * 128 * 128 * NC;
  float* pooled4 = pooled3 + (size_t)6 * 64 * 64 * NC;
  float* pooled5 = pooled4 + (size_t)6 * 32 * 32 * NC;
  float* pooled[6] = {nullptr, pooled1, pooled2, pooled3, pooled4, pooled5};
  static const int offs[6] = {0, 262144, 327680, 344064, 348160, 349184};

  // K1: transpose level 0 + pooled level 1
  hipLaunchKernelGGL(k_transpose_pool, dim3(6 * 1024), dim3(256), 0, stream,
                     feat, pool_t, pooled1);

  // K2: pool chain levels 2..5
  for (int l = 2; l <= 5; ++l) {
    int Rin = 512 >> (l - 1);
    int Rout = 512 >> l;
    int logRout = 9 - l;
    int n = 6 * Rout * Rout * NC;
    hipLaunchKernelGGL(k_pool, dim3((n + 255) / 256), dim3(256), 0, stream,
                       pooled[l - 1], pooled[l], Rin, logRout, n);
  }

  // K3: specular filter levels 1..5 -> pool_t slots
  for (int l = 1; l <= 5; ++l) {
    int R = 512 >> l;
    int logR = 9 - l;
    double rough_d = 0.03 + 0.192 * (double)l;   // linspace(0.03,0.99,6)
    float r32 = (float)rough_d;                  // matches float32 _roughness
    double alpha = (double)r32 * (double)r32;    // float(rough)**2 in python
    float a2 = (float)(alpha * alpha);
    int n = 6 * R * R;
    hipLaunchKernelGGL(k_filter, dim3((n + 255) / 256), dim3(256), 0, stream,
                       pooled[l], pool_t + (size_t)offs[l] * NC, R, logR, a2, n);
  }

  // K4: fetch
  hipLaunchKernelGGL(k_fetch, dim3((B + 255) / 256), dim3(256), 0, stream,
                     pool_t, wv, rv, out, B);
}

// Round 2
// 481.947 us; speedup vs baseline: 1.4368x; 1.4368x over previous
//
#include <hip/hip_runtime.h>
#include <cstddef>

#define PI_F 3.14159265358979323846f
#define TOTAL_TEX 349440
#define NC 32

__constant__ int c_offs[6] = {0, 262144, 327680, 344064, 348160, 349184};

// ---------------------------------------------------------------------------
// K1: transpose feature (C,6,512,512) -> pool_t level0 [6][512*512][C]
//     and produce pooled1 [6][256*256][C] (2x2 avg) in the same pass.
// ---------------------------------------------------------------------------
__global__ __launch_bounds__(256) void k_transpose_pool(
    const float* __restrict__ feat, float* __restrict__ pool_t,
    float* __restrict__ pooled1)
{
  __shared__ float tile[256 * 33];
  int blk = blockIdx.x;
  int f = blk >> 10;          // 1024 tiles per face
  int t = blk & 1023;
  int gy0 = (t >> 5) << 4;
  int gx0 = (t & 31) << 4;
  int tid = threadIdx.x;
  int ly = tid >> 4, lx = tid & 15;

  for (int c = 0; c < NC; ++c) {
    tile[(ly * 16 + lx) * 33 + c] =
        feat[(((size_t)c * 6 + f) * 512 + (gy0 + ly)) * 512 + (gx0 + lx)];
  }
  __syncthreads();

  size_t base0 = ((size_t)f * TOTAL_TEX + (size_t)gy0 * 512 + gx0) * NC;
  for (int it = 0; it < 32; ++it) {
    int e = it * 256 + tid;
    int c = e & 31;
    int x = (e >> 5) & 15;
    int y = e >> 9;
    pool_t[base0 + ((size_t)y * 512 + x) * NC + c] = tile[(y * 16 + x) * 33 + c];
  }

  size_t base1 = ((size_t)f * 65536 + (size_t)(gy0 >> 1) * 256 + (gx0 >> 1)) * NC;
  for (int it = 0; it < 8; ++it) {
    int e = it * 256 + tid;
    int c = e & 31;
    int x1 = (e >> 5) & 7;
    int y1 = e >> 8;
    float v = 0.25f * ((tile[((2 * y1) * 16 + 2 * x1) * 33 + c] +
                        tile[((2 * y1) * 16 + 2 * x1 + 1) * 33 + c]) +
                       (tile[((2 * y1 + 1) * 16 + 2 * x1) * 33 + c] +
                        tile[((2 * y1 + 1) * 16 + 2 * x1 + 1) * 33 + c]));
    pooled1[base1 + ((size_t)y1 * 256 + x1) * NC + c] = v;
  }
}

// ---------------------------------------------------------------------------
// K2: generic 2x2 avg pool, both sides [6][R*R][C] channel-innermost.
// ---------------------------------------------------------------------------
__global__ __launch_bounds__(256) void k_pool(
    const float* __restrict__ in, float* __restrict__ out,
    int Rin, int logRout, int n)
{
  int t = blockIdx.x * 256 + threadIdx.x;
  if (t >= n) return;
  int c = t & 31;
  int rem = t >> 5;
  int Rout = Rin >> 1;
  int x = rem & (Rout - 1);
  rem >>= logRout;
  int y = rem & (Rout - 1);
  int f = rem >> logRout;
  size_t b = (((size_t)f * Rin + 2 * y) * Rin + 2 * x) * NC + c;
  size_t rowstep = (size_t)Rin * NC;
  out[t] = 0.25f * ((in[b] + in[b + NC]) + (in[b + rowstep] + in[b + rowstep + NC]));
}

// ---------------------------------------------------------------------------
// K3: 5x5 GGX specular filter, lane-remapped for coalescing.
// Block = 32 pixels x 8 channel-groups. lane = p_local*8 + cg so that the 8
// lanes of one pixel read one texel's contiguous 128B, and a wave covers 8
// consecutive texels (1 KiB coalesced per wave load).
// Phase 1 precomputes GGX weights per (pixel, tap) into LDS (shared by cg).
// ---------------------------------------------------------------------------
__device__ inline float3 face_dir_norm(int f, int i, int j, float inv2R)
{
  float u = ((float)j + 0.5f) * inv2R - 1.0f;  // uu = t[j]
  float v = ((float)i + 0.5f) * inv2R - 1.0f;  // vv = t[i]
  float x, y, z;
  switch (f) {
    case 0: x = 1.0f;  y = -v; z = -u;   break;
    case 1: x = -1.0f; y = -v; z = u;    break;
    case 2: x = u;  y = 1.0f;  z = v;    break;
    case 3: x = u;  y = -1.0f; z = -v;   break;
    case 4: x = u;  y = -v;    z = 1.0f; break;
    default: x = -u; y = -v;   z = -1.0f; break;
  }
  float s = 1.0f / sqrtf(x * x + y * y + z * z);
  float3 o; o.x = x * s; o.y = y * s; o.z = z * s;
  return o;
}

__global__ __launch_bounds__(256) void k_filter2(
    const float* __restrict__ in, float* __restrict__ out,
    int R, int logR, float a2)
{
  __shared__ float wlds[32 * 26];   // [p_local][tap], padded to 26
  int tid = threadIdx.x;
  int p0 = blockIdx.x << 5;         // 32 pixels per block
  float inv2R = 2.0f / (float)R;

  // ---- phase 1: weights (thread = (pixel, tap-group)) ----
  {
    int pl = tid & 31;
    int tg = tid >> 5;              // 0..7
    int p = p0 + pl;
    int j = p & (R - 1);
    int i = (p >> logR) & (R - 1);
    int f = p >> (2 * logR);
    float3 dc = face_dir_norm(f, i, j, inv2R);
    for (int tap = tg; tap < 25; tap += 8) {
      int di = tap / 5 - 2;
      int dj = tap - (tap / 5) * 5 - 2;
      int ii = min(max(i + di, 0), R - 1);
      int jj = min(max(j + dj, 0), R - 1);
      float3 dn = face_dir_norm(f, ii, jj, inv2R);
      float cs = dc.x * dn.x + dc.y * dn.y + dc.z * dn.z;
      cs = fminf(fmaxf(cs, -1.0f), 1.0f);
      float den = cs * cs * (a2 - 1.0f) + 1.0f;
      float w = (cs > 0.0f) ? (a2 / (PI_F * den * den)) : 0.0f;
      wlds[pl * 26 + tap] = w;
    }
  }
  __syncthreads();

  // ---- phase 2: accumulate (thread = (pixel, channel-group)) ----
  int cg = tid & 7;
  int pl = tid >> 3;
  int p = p0 + pl;
  int j = p & (R - 1);
  int i = (p >> logR) & (R - 1);
  int f = p >> (2 * logR);
  const float4* fbase = (const float4*)(in + (((size_t)f << (2 * logR)) * NC));

  float4 acc; acc.x = acc.y = acc.z = acc.w = 0.0f;
  float wsum = 0.0f;
#pragma unroll
  for (int di = -2; di <= 2; ++di) {
    int ii = min(max(i + di, 0), R - 1);
    int rowb = ii * R;
#pragma unroll
    for (int dj = -2; dj <= 2; ++dj) {
      int jj = min(max(j + dj, 0), R - 1);
      int tap = (di + 2) * 5 + (dj + 2);
      float w = wlds[pl * 26 + tap];
      wsum += w;
      float4 v = fbase[(size_t)(rowb + jj) * 8 + cg];
      acc.x += w * v.x; acc.y += w * v.y; acc.z += w * v.z; acc.w += w * v.w;
    }
  }
  float s = 1.0f / fmaxf(wsum, 1e-8f);
  float4 q; q.x = acc.x * s; q.y = acc.y * s; q.z = acc.z * s; q.w = acc.w * s;
  float4* o = (float4*)(out + ((size_t)f * TOTAL_TEX + (size_t)(i * R + j)) * NC);
  o[cg] = q;
}

// ---------------------------------------------------------------------------
// K4: fetch, lane-remapped: thread = (sample, channel-group). 8 lanes of a
// sample read contiguous 128B; per-wave tap load = 8 segments instead of 64
// divergent lines. Per-sample math recomputed in all 8 lanes (cheap VALU).
// ---------------------------------------------------------------------------
__global__ __launch_bounds__(256) void k_fetch2(
    const float* __restrict__ pool_t, const float* __restrict__ wv,
    const float* __restrict__ rv, float* __restrict__ out, int B)
{
  int t = blockIdx.x * 256 + threadIdx.x;
  int cg = t & 7;
  int b = t >> 3;
  if (b >= B) return;

  float dx = wv[3 * b + 0] * 2.0f - 1.0f;
  float dy = wv[3 * b + 1] * 2.0f - 1.0f;
  float dz = wv[3 * b + 2] * 2.0f - 1.0f;
  float ax = fabsf(dx), ay = fabsf(dy), az = fabsf(dz);
  bool condx = (ax >= ay) && (ax >= az);
  bool condy = (ay >= az) && !condx;
  float ma = condx ? ax : (condy ? ay : az);
  int face = condx ? (dx > 0.0f ? 0 : 1)
                   : (condy ? (dy > 0.0f ? 2 : 3) : (dz > 0.0f ? 4 : 5));
  float un = condx ? (dx > 0.0f ? -dz : dz)
                   : (condy ? dx : (dz > 0.0f ? dx : -dx));
  float vn = condx ? -dy : (condy ? (dy > 0.0f ? dz : -dz) : -dy);
  float u01 = (un / ma + 1.0f) * 0.5f;
  float v01 = (vn / ma + 1.0f) * 0.5f;

  float rr = rv[b];
  float lev_f = fminf(fmaxf((rr - 0.03f) / (0.99f - 0.03f), 0.0f), 1.0f) * 5.0f;
  int l0 = (int)floorf(lev_f);
  l0 = min(max(l0, 0), 5);
  int l1 = min(l0 + 1, 5);
  float tt = lev_f - (float)l0;

  float4 acc; acc.x = acc.y = acc.z = acc.w = 0.0f;
  int   lvs[2] = {l0, l1};
  float lws[2] = {1.0f - tt, tt};
#pragma unroll
  for (int s = 0; s < 2; ++s) {
    int l = lvs[s];
    float wl = lws[s];
    int res = 512 >> l;
    float rf = (float)res;
    float x = fminf(fmaxf(u01 * rf - 0.5f, 0.0f), rf - 1.0f);
    float y = fminf(fmaxf(v01 * rf - 0.5f, 0.0f), rf - 1.0f);
    int x0 = (int)floorf(x), y0 = (int)floorf(y);
    int x1 = min(x0 + 1, res - 1), y1 = min(y0 + 1, res - 1);
    float fx = x - (float)x0, fy = y - (float)y0;
    const float4* base4 =
        (const float4*)(pool_t + ((size_t)face * TOTAL_TEX + c_offs[l]) * NC);
    float w00 = wl * (1.0f - fx) * (1.0f - fy);
    float w01 = wl * fx * (1.0f - fy);
    float w10 = wl * (1.0f - fx) * fy;
    float w11 = wl * fx * fy;
    float4 a = base4[(size_t)(y0 * res + x0) * 8 + cg];
    float4 bq = base4[(size_t)(y0 * res + x1) * 8 + cg];
    float4 cq = base4[(size_t)(y1 * res + x0) * 8 + cg];
    float4 dq = base4[(size_t)(y1 * res + x1) * 8 + cg];
    acc.x += w00 * a.x + w01 * bq.x + w10 * cq.x + w11 * dq.x;
    acc.y += w00 * a.y + w01 * bq.y + w10 * cq.y + w11 * dq.y;
    acc.z += w00 * a.z + w01 * bq.z + w10 * cq.z + w11 * dq.z;
    acc.w += w00 * a.w + w01 * bq.w + w10 * cq.w + w11 * dq.w;
  }
  ((float4*)(out + (size_t)b * NC))[cg] = acc;
}

// ---------------------------------------------------------------------------
extern "C" void kernel_launch(void* const* d_in, const int* in_sizes, int n_in,
                              void* d_out, int out_size, void* d_ws, size_t ws_size,
                              hipStream_t stream)
{
  const float* feat = (const float*)d_in[0];
  const float* wv   = (const float*)d_in[1];
  const float* rv   = (const float*)d_in[2];
  float* out = (float*)d_out;
  int B = in_sizes[1] / 3;

  float* pool_t = (float*)d_ws;
  const size_t POOLT = (size_t)6 * TOTAL_TEX * NC;
  float* pooled1 = pool_t + POOLT;
  float* pooled2 = pooled1 + (size_t)6 * 256 * 256 * NC;
  float* pooled3 = pooled2 + (size_t)6 * 128 * 128 * NC;
  float* pooled4 = pooled3 + (size_t)6 * 64 * 64 * NC;
  float* pooled5 = pooled4 + (size_t)6 * 32 * 32 * NC;
  float* pooled[6] = {nullptr, pooled1, pooled2, pooled3, pooled4, pooled5};
  static const int offs[6] = {0, 262144, 327680, 344064, 348160, 349184};

  hipLaunchKernelGGL(k_transpose_pool, dim3(6 * 1024), dim3(256), 0, stream,
                     feat, pool_t, pooled1);

  for (int l = 2; l <= 5; ++l) {
    int Rin = 512 >> (l - 1);
    int Rout = 512 >> l;
    int logRout = 9 - l;
    int n = 6 * Rout * Rout * NC;
    hipLaunchKernelGGL(k_pool, dim3((n + 255) / 256), dim3(256), 0, stream,
                       pooled[l - 1], pooled[l], Rin, logRout, n);
  }

  for (int l = 1; l <= 5; ++l) {
    int R = 512 >> l;
    int logR = 9 - l;
    double rough_d = 0.03 + 0.192 * (double)l;   // linspace(0.03,0.99,6)
    float r32 = (float)rough_d;
    double alpha = (double)r32 * (double)r32;
    float a2 = (float)(alpha * alpha);
    int npix = 6 * R * R;
    hipLaunchKernelGGL(k_filter2, dim3(npix / 32), dim3(256), 0, stream,
                       pooled[l], pool_t + (size_t)offs[l] * NC, R, logR, a2);
  }

  hipLaunchKernelGGL(k_fetch2, dim3((B * 8 + 255) / 256), dim3(256), 0, stream,
                     pool_t, wv, rv, out, B);
}

// Round 3
// 443.717 us; speedup vs baseline: 1.5606x; 1.0862x over previous
//
#include <hip/hip_runtime.h>
#include <cstddef>

#define PI_F 3.14159265358979323846f
#define TOTAL_TEX 349440
#define NC 32
#define LP 257   // LDS pad stride for K1 (257 % 32 == 1 -> conflict-free writes)

__constant__ int c_offs[6] = {0, 262144, 327680, 344064, 348160, 349184};

// ---- bf16 helpers (RNE) ---------------------------------------------------
static __device__ inline unsigned int f2bf(float x) {
  union { float f; unsigned int u; } v; v.f = x;
  return (v.u + 0x7FFFu + ((v.u >> 16) & 1u)) >> 16;
}
static __device__ inline unsigned int pack2(float lo, float hi) {
  return f2bf(lo) | (f2bf(hi) << 16);
}
static __device__ inline float4 bf4(uint2 q) {
  union { unsigned int u; float f; } a;
  float4 r;
  a.u = q.x << 16;          r.x = a.f;
  a.u = q.x & 0xFFFF0000u;  r.y = a.f;
  a.u = q.y << 16;          r.z = a.f;
  a.u = q.y & 0xFFFF0000u;  r.w = a.f;
  return r;
}

// ---------------------------------------------------------------------------
// K1: transpose feature (C,6,512,512) -> bf16 pool level0 [6][512*512][C]
//     and produce fp32 pooled1 [6][256*256][C] (2x2 avg) in the same pass.
// Tile = 64x4 pixels, 256 threads. Loads: 256B/wave contiguous per channel.
// Stores: 512B/wave contiguous bf16 dwordx2.
// ---------------------------------------------------------------------------
__global__ __launch_bounds__(256) void k_transpose_pool(
    const float* __restrict__ feat, unsigned short* __restrict__ pool0,
    float* __restrict__ pooled1)
{
  __shared__ float tile[32 * LP];
  int blk = blockIdx.x;
  int tx = blk & 7;            // 8 x-tiles of 64
  int rem = blk >> 3;
  int ty = rem & 127;          // 128 y-tiles of 4
  int f = rem >> 7;
  int gx0 = tx << 6, gy0 = ty << 2;
  int tid = threadIdx.x;
  int lx = tid & 63, ly = tid >> 6;
  int pix = ly * 64 + lx;

  const float* fp = feat + ((size_t)f * 512 + (gy0 + ly)) * 512 + gx0 + lx;
#pragma unroll
  for (int c = 0; c < 32; ++c) {
    tile[c * LP + pix] = fp[(size_t)c * (6 * 512 * 512)];
  }
  __syncthreads();

  // level-0 bf16 transposed store
  size_t rowbase = ((size_t)f * TOTAL_TEX + (size_t)gy0 * 512 + gx0) * NC;
#pragma unroll
  for (int it = 0; it < 8; ++it) {
    int q = it * 256 + tid;          // 0..2047
    int texel = q >> 3, cg = q & 7;
    int tyy = texel >> 6, txx = texel & 63;
    float v0 = tile[(cg * 4 + 0) * LP + texel];
    float v1 = tile[(cg * 4 + 1) * LP + texel];
    float v2 = tile[(cg * 4 + 2) * LP + texel];
    float v3 = tile[(cg * 4 + 3) * LP + texel];
    uint2 pk; pk.x = pack2(v0, v1); pk.y = pack2(v2, v3);
    *(uint2*)(pool0 + rowbase + ((size_t)tyy * 512 + txx) * NC + cg * 4) = pk;
  }

  // fp32 pooled level-1 (32x2 pooled texels)
  size_t pbase = ((size_t)f * 65536 + (size_t)(gy0 >> 1) * 256 + (gx0 >> 1)) * NC;
#pragma unroll
  for (int it = 0; it < 8; ++it) {
    int e = it * 256 + tid;          // c fast(32), px(32), py(2)
    int c = e & 31, px = (e >> 5) & 31, py = e >> 10;
    int b0 = (2 * py) * 64 + 2 * px;
    float v = 0.25f * ((tile[c * LP + b0] + tile[c * LP + b0 + 1]) +
                       (tile[c * LP + b0 + 64] + tile[c * LP + b0 + 65]));
    pooled1[pbase + ((size_t)py * 256 + px) * NC + c] = v;
  }
}

// ---------------------------------------------------------------------------
// K2: generic 2x2 avg pool, fp32 -> fp32, channel-innermost.
// ---------------------------------------------------------------------------
__global__ __launch_bounds__(256) void k_pool(
    const float* __restrict__ in, float* __restrict__ out,
    int Rin, int logRout, int n)
{
  int t = blockIdx.x * 256 + threadIdx.x;
  if (t >= n) return;
  int c = t & 31;
  int rem = t >> 5;
  int Rout = Rin >> 1;
  int x = rem & (Rout - 1);
  rem >>= logRout;
  int y = rem & (Rout - 1);
  int f = rem >> logRout;
  size_t b = (((size_t)f * Rin + 2 * y) * Rin + 2 * x) * NC + c;
  size_t rowstep = (size_t)Rin * NC;
  out[t] = 0.25f * ((in[b] + in[b + NC]) + (in[b + rowstep] + in[b + rowstep + NC]));
}

// ---------------------------------------------------------------------------
// K3: 5x5 GGX specular filter, lane-remapped; reads fp32 pooled, writes bf16.
// ---------------------------------------------------------------------------
__device__ inline float3 face_dir_norm(int f, int i, int j, float inv2R)
{
  float u = ((float)j + 0.5f) * inv2R - 1.0f;
  float v = ((float)i + 0.5f) * inv2R - 1.0f;
  float x, y, z;
  switch (f) {
    case 0: x = 1.0f;  y = -v; z = -u;   break;
    case 1: x = -1.0f; y = -v; z = u;    break;
    case 2: x = u;  y = 1.0f;  z = v;    break;
    case 3: x = u;  y = -1.0f; z = -v;   break;
    case 4: x = u;  y = -v;    z = 1.0f; break;
    default: x = -u; y = -v;   z = -1.0f; break;
  }
  float s = 1.0f / sqrtf(x * x + y * y + z * z);
  float3 o; o.x = x * s; o.y = y * s; o.z = z * s;
  return o;
}

__global__ __launch_bounds__(256) void k_filter2(
    const float* __restrict__ in, unsigned short* __restrict__ out,
    int R, int logR, float a2)
{
  __shared__ float wlds[32 * 26];
  int tid = threadIdx.x;
  int p0 = blockIdx.x << 5;
  float inv2R = 2.0f / (float)R;

  {
    int pl = tid & 31;
    int tg = tid >> 5;
    int p = p0 + pl;
    int j = p & (R - 1);
    int i = (p >> logR) & (R - 1);
    int f = p >> (2 * logR);
    float3 dc = face_dir_norm(f, i, j, inv2R);
    for (int tap = tg; tap < 25; tap += 8) {
      int di = tap / 5 - 2;
      int dj = tap - (tap / 5) * 5 - 2;
      int ii = min(max(i + di, 0), R - 1);
      int jj = min(max(j + dj, 0), R - 1);
      float3 dn = face_dir_norm(f, ii, jj, inv2R);
      float cs = dc.x * dn.x + dc.y * dn.y + dc.z * dn.z;
      cs = fminf(fmaxf(cs, -1.0f), 1.0f);
      float den = cs * cs * (a2 - 1.0f) + 1.0f;
      float w = (cs > 0.0f) ? (a2 / (PI_F * den * den)) : 0.0f;
      wlds[pl * 26 + tap] = w;
    }
  }
  __syncthreads();

  int cg = tid & 7;
  int pl = tid >> 3;
  int p = p0 + pl;
  int j = p & (R - 1);
  int i = (p >> logR) & (R - 1);
  int f = p >> (2 * logR);
  const float4* fbase = (const float4*)(in + (((size_t)f << (2 * logR)) * NC));

  float4 acc; acc.x = acc.y = acc.z = acc.w = 0.0f;
  float wsum = 0.0f;
#pragma unroll
  for (int di = -2; di <= 2; ++di) {
    int ii = min(max(i + di, 0), R - 1);
    int rowb = ii * R;
#pragma unroll
    for (int dj = -2; dj <= 2; ++dj) {
      int jj = min(max(j + dj, 0), R - 1);
      int tap = (di + 2) * 5 + (dj + 2);
      float w = wlds[pl * 26 + tap];
      wsum += w;
      float4 v = fbase[(size_t)(rowb + jj) * 8 + cg];
      acc.x += w * v.x; acc.y += w * v.y; acc.z += w * v.z; acc.w += w * v.w;
    }
  }
  float s = 1.0f / fmaxf(wsum, 1e-8f);
  uint2 pk;
  pk.x = pack2(acc.x * s, acc.y * s);
  pk.y = pack2(acc.z * s, acc.w * s);
  ((uint2*)(out + ((size_t)f * TOTAL_TEX + (size_t)(i * R + j)) * NC))[cg] = pk;
}

// ---------------------------------------------------------------------------
// K4: fetch from bf16 pool. thread = (sample, channel-group of 4).
// 8 lanes cover one 64B texel; per-tap wave load = 8 x 64B segments.
// ---------------------------------------------------------------------------
__global__ __launch_bounds__(256) void k_fetch2(
    const unsigned short* __restrict__ pool, const float* __restrict__ wv,
    const float* __restrict__ rv, float* __restrict__ out, int B)
{
  int t = blockIdx.x * 256 + threadIdx.x;
  int cg = t & 7;
  int b = t >> 3;
  if (b >= B) return;

  float dx = wv[3 * b + 0] * 2.0f - 1.0f;
  float dy = wv[3 * b + 1] * 2.0f - 1.0f;
  float dz = wv[3 * b + 2] * 2.0f - 1.0f;
  float ax = fabsf(dx), ay = fabsf(dy), az = fabsf(dz);
  bool condx = (ax >= ay) && (ax >= az);
  bool condy = (ay >= az) && !condx;
  float ma = condx ? ax : (condy ? ay : az);
  int face = condx ? (dx > 0.0f ? 0 : 1)
                   : (condy ? (dy > 0.0f ? 2 : 3) : (dz > 0.0f ? 4 : 5));
  float un = condx ? (dx > 0.0f ? -dz : dz)
                   : (condy ? dx : (dz > 0.0f ? dx : -dx));
  float vn = condx ? -dy : (condy ? (dy > 0.0f ? dz : -dz) : -dy);
  float u01 = (un / ma + 1.0f) * 0.5f;
  float v01 = (vn / ma + 1.0f) * 0.5f;

  float rr = rv[b];
  float lev_f = fminf(fmaxf((rr - 0.03f) / (0.99f - 0.03f), 0.0f), 1.0f) * 5.0f;
  int l0 = (int)floorf(lev_f);
  l0 = min(max(l0, 0), 5);
  int l1 = min(l0 + 1, 5);
  float tt = lev_f - (float)l0;

  float4 acc; acc.x = acc.y = acc.z = acc.w = 0.0f;
  int   lvs[2] = {l0, l1};
  float lws[2] = {1.0f - tt, tt};
#pragma unroll
  for (int s = 0; s < 2; ++s) {
    int l = lvs[s];
    float wl = lws[s];
    int res = 512 >> l;
    float rf = (float)res;
    float x = fminf(fmaxf(u01 * rf - 0.5f, 0.0f), rf - 1.0f);
    float y = fminf(fmaxf(v01 * rf - 0.5f, 0.0f), rf - 1.0f);
    int x0 = (int)floorf(x), y0 = (int)floorf(y);
    int x1 = min(x0 + 1, res - 1), y1 = min(y0 + 1, res - 1);
    float fx = x - (float)x0, fy = y - (float)y0;
    const uint2* base8 =
        (const uint2*)(pool + ((size_t)face * TOTAL_TEX + c_offs[l]) * NC);
    float w00 = wl * (1.0f - fx) * (1.0f - fy);
    float w01 = wl * fx * (1.0f - fy);
    float w10 = wl * (1.0f - fx) * fy;
    float w11 = wl * fx * fy;
    float4 a = bf4(base8[(size_t)(y0 * res + x0) * 8 + cg]);
    float4 bq = bf4(base8[(size_t)(y0 * res + x1) * 8 + cg]);
    float4 cq = bf4(base8[(size_t)(y1 * res + x0) * 8 + cg]);
    float4 dq = bf4(base8[(size_t)(y1 * res + x1) * 8 + cg]);
    acc.x += w00 * a.x + w01 * bq.x + w10 * cq.x + w11 * dq.x;
    acc.y += w00 * a.y + w01 * bq.y + w10 * cq.y + w11 * dq.y;
    acc.z += w00 * a.z + w01 * bq.z + w10 * cq.z + w11 * dq.z;
    acc.w += w00 * a.w + w01 * bq.w + w10 * cq.w + w11 * dq.w;
  }
  ((float4*)(out + (size_t)b * NC))[cg] = acc;
}

// ---------------------------------------------------------------------------
extern "C" void kernel_launch(void* const* d_in, const int* in_sizes, int n_in,
                              void* d_out, int out_size, void* d_ws, size_t ws_size,
                              hipStream_t stream)
{
  const float* feat = (const float*)d_in[0];
  const float* wv   = (const float*)d_in[1];
  const float* rv   = (const float*)d_in[2];
  float* out = (float*)d_out;
  int B = in_sizes[1] / 3;

  // ws layout: bf16 pool (134.2 MB) then fp32 pooled scratch (67.0 MB)
  unsigned short* pool_t = (unsigned short*)d_ws;
  const size_t POOLT = (size_t)6 * TOTAL_TEX * NC;      // bf16 elements
  float* pooled1 = (float*)(pool_t + POOLT);            // byte offset % 4 == 0
  float* pooled2 = pooled1 + (size_t)6 * 256 * 256 * NC;
  float* pooled3 = pooled2 + (size_t)6 * 128 * 128 * NC;
  float* pooled4 = pooled3 + (size_t)6 * 64 * 64 * NC;
  float* pooled5 = pooled4 + (size_t)6 * 32 * 32 * NC;
  float* pooled[6] = {nullptr, pooled1, pooled2, pooled3, pooled4, pooled5};
  static const int offs[6] = {0, 262144, 327680, 344064, 348160, 349184};

  hipLaunchKernelGGL(k_transpose_pool, dim3(6 * 8 * 128), dim3(256), 0, stream,
                     feat, pool_t, pooled1);

  for (int l = 2; l <= 5; ++l) {
    int Rin = 512 >> (l - 1);
    int Rout = 512 >> l;
    int logRout = 9 - l;
    int n = 6 * Rout * Rout * NC;
    hipLaunchKernelGGL(k_pool, dim3((n + 255) / 256), dim3(256), 0, stream,
                       pooled[l - 1], pooled[l], Rin, logRout, n);
  }

  for (int l = 1; l <= 5; ++l) {
    int R = 512 >> l;
    int logR = 9 - l;
    double rough_d = 0.03 + 0.192 * (double)l;   // linspace(0.03,0.99,6)
    float r32 = (float)rough_d;
    double alpha = (double)r32 * (double)r32;
    float a2 = (float)(alpha * alpha);
    int npix = 6 * R * R;
    hipLaunchKernelGGL(k_filter2, dim3(npix / 32), dim3(256), 0, stream,
                       pooled[l], pool_t + (size_t)offs[l] * NC, R, logR, a2);
  }

  hipLaunchKernelGGL(k_fetch2, dim3((B * 8 + 255) / 256), dim3(256), 0, stream,
                     pool_t, wv, rv, out, B);
}